// Round 12
// baseline (161.200 us; speedup 1.0000x reference)
//
#include <hip/hip_runtime.h>

// LaterallyConnectedLayer: B=16, NUM_FM=64, N=4, NF=256, H=W=32, KS=5. fp32 I/O.
//   w1[i][o][k]   = minmax5x5( K[i][o] )
//   wsum[o][g][k] = sum_n w1[64n+g][o][k]
//   score[b,o]    = (sum-1024*min)/(max-min) over conv_same(A[b,:],wsum[o,:])*S[o]
//   n*[b,f]       = argmax_n score[b,64n+f]
//   out[b,f]      = (1/64) sum_g conv_same(A[b,g], w1[ig_g][ig_f]), ig_x = 64n*_x + x
// Both convs are implicit GEMMs on mfma_f32_16x16x32_bf16 with fp32 hi/lo split
// (hh+hl+lh). K-dim order: k_global = dydx*64 + g -> chunk ks = dydx*2+(g>=32),
// in-chunk k = quad*8+j with g = (ks&1)*32+quad*8+j. Fragment layouts per m89.

#define NFM 64
#define NMX 4
#define NFC 256
#define HW 1024
#define KK 25

typedef unsigned short u16;
typedef short short8 __attribute__((ext_vector_type(8)));
typedef float f32x4 __attribute__((ext_vector_type(4)));

__device__ __forceinline__ u16 f2bfbits(float f) {
    unsigned int u = __float_as_uint(f);
    u += 0x7fffu + ((u >> 16) & 1u);   // RNE
    return (u16)(u >> 16);
}
__device__ __forceinline__ float bf2f(u16 v) {
    return __uint_as_float(((unsigned int)v) << 16);
}

// --- kprep: wsum2[g][k][o] = sum_n minmax5x5(K[64n+g][o]) -------------------
// grid 256 = (g 0..63) x (o-quarter 0..3). Flush layout o-fastest (coalesced).
__global__ __launch_bounds__(256) void kprep(const float* __restrict__ K,
                                             float* __restrict__ wsum2) {
    __shared__ __align__(16) float buf[64 * KK];
    int g = blockIdx.x & 63, o0 = (blockIdx.x >> 6) * 64;
    int t = threadIdx.x;
    float wacc[KK];
#pragma unroll
    for (int k = 0; k < KK; ++k) wacc[k] = 0.f;

    for (int n = 0; n < NMX; ++n) {
        int i = n * NFM + g;
        const float4* src = (const float4*)(K + (i * NFC + o0) * KK);  // 400 f4
        __syncthreads();
        ((float4*)buf)[t] = src[t];
        if (t < 144) ((float4*)buf)[t + 256] = src[t + 256];
        __syncthreads();
        if (t < 64) {
            float v[KK];
            float mn = 1e30f, mx = -1e30f;
#pragma unroll
            for (int k = 0; k < KK; ++k) {
                v[k] = buf[t * KK + k];
                mn = fminf(mn, v[k]);
                mx = fmaxf(mx, v[k]);
            }
            float d = mx - mn;
            float r = d > 0.f ? 1.f / d : 0.f;
#pragma unroll
            for (int k = 0; k < KK; ++k) wacc[k] += (v[k] - mn) * r;
        }
    }
    __syncthreads();
    if (t < 64) {
#pragma unroll
        for (int k = 0; k < KK; ++k) buf[t * KK + k] = wacc[k];
    }
    __syncthreads();
    // wsum2[(g*25 + k)*256 + o]  — 64-wide coalesced runs
    for (int idx = t; idx < 1600; idx += 256) {
        int k = idx >> 6, ol = idx & 63;
        wsum2[(g * KK + k) * NFC + o0 + ol] = buf[ol * KK + k];
    }
}

// --- kpackW: wsum2 -> Wpk via LDS transpose. grid (25 dydx, 16 ot) ----------
// Phase 1: gather wsum2[g][dydx][o-tile] (coalesced o-runs) into LDS.
// Phase 2: emit 2 chunks (gh=0/1) in MFMA A-fragment order, hi/lo.
__global__ __launch_bounds__(256) void kpackW(const float* __restrict__ wsum2,
                                              char* __restrict__ Wpk) {
    __shared__ float wlds[64 * 16];
    int dydx = blockIdx.x, ot = blockIdx.y, t = threadIdx.x;
    int o15 = t & 15, gq = t >> 4;
#pragma unroll
    for (int e = 0; e < 4; ++e) {
        int g = e * 16 + gq;
        wlds[g * 16 + o15] = wsum2[(g * KK + dydx) * NFC + ot * 16 + o15];
    }
    __syncthreads();
    int gh = t >> 7, l = t & 63;      // gh 0..1, lane l
    int quad = l >> 4, oo = l & 15;
    short8 hs, ls;
#pragma unroll
    for (int j = 0; j < 8; ++j) {
        float v = wlds[(gh * 32 + quad * 8 + j) * 16 + oo];
        u16 h = f2bfbits(v);
        hs[j] = (short)h;
        ls[j] = (short)f2bfbits(v - bf2f(h));
    }
    char* cb = Wpk + (ot * 50 + dydx * 2 + gh) * 2048 + l * 16;
    *(short8*)cb = hs;
    *(short8*)(cb + 1024) = ls;
}

// --- kscore: grid (32 y, 16 b), 512 thr, 2 blocks/CU ------------------------
// Wave = 2 M-tiles (32 o) x 2 npos (1 row x 2 ntiles); B-frags shared across
// both M-tiles in-register (halves LDS reads); next-ks weight prefetch.
__global__ __launch_bounds__(512, 4) void kscore(const float* __restrict__ A,
                                                 const char* __restrict__ Wpk,
                                                 float* __restrict__ part) {
    __shared__ u16 slabh[5 * 36 * 72];   // 25920 B
    __shared__ u16 slabl[5 * 36 * 72];
    int t = threadIdx.x;
    int y = blockIdx.x, b = blockIdx.y;
    int lane = t & 63;
    int wv = __builtin_amdgcn_readfirstlane(t >> 6);   // 0..7
    int n15 = lane & 15, quad = lane >> 4;

    const float* Ab = A + b * NFM * HW;
    for (int ry = 0; ry < 5; ++ry) {
        int gy = y - 2 + ry;
        bool rowok = (gy >= 0) && (gy < 32);
        for (int c = 0; c < 5; ++c) {
            int id2 = c * 512 + t;               // g*36 + xi, < 2304
            if (id2 < 2304) {
                int g = (id2 * 3641) >> 17;      // exact /36 for id2<2304
                int xi = id2 - g * 36;
                float v = 0.f;
                if (rowok && xi >= 2 && xi < 34)
                    v = Ab[g * HW + gy * 32 + xi - 2];
                u16 h = f2bfbits(v);
                u16 l = f2bfbits(v - bf2f(h));
                int idx = (ry * 36 + xi) * 72 + g;
                slabh[idx] = h;
                slabl[idx] = l;
            }
        }
    }
    __syncthreads();

    f32x4 acc[2][2];
#pragma unroll
    for (int m = 0; m < 2; ++m)
#pragma unroll
        for (int p = 0; p < 2; ++p)
#pragma unroll
            for (int r = 0; r < 4; ++r) acc[m][p][r] = 0.f;

    const char* wbase0 = Wpk + (wv * 2) * 50 * 2048 + lane * 16;
    const char* wbase1 = wbase0 + 50 * 2048;
    short8 cah0 = *(const short8*)(wbase0);
    short8 cal0 = *(const short8*)(wbase0 + 1024);
    short8 cah1 = *(const short8*)(wbase1);
    short8 cal1 = *(const short8*)(wbase1 + 1024);

    for (int ks = 0; ks < 50; ++ks) {
        int ksn = ks < 49 ? ks + 1 : 49;
        const char* nb0 = wbase0 + (ksn << 11);
        const char* nb1 = wbase1 + (ksn << 11);
        short8 nah0 = *(const short8*)nb0;
        short8 nal0 = *(const short8*)(nb0 + 1024);
        short8 nah1 = *(const short8*)nb1;
        short8 nal1 = *(const short8*)(nb1 + 1024);

        int dydx = ks >> 1;
        int gh = (ks & 1) * 32;
        int dy = dydx / 5, dx = dydx - dy * 5;
        short8 bh[2], bl[2];
#pragma unroll
        for (int p = 0; p < 2; ++p) {
            int addr = (dy * 36 + p * 16 + n15 + dx) * 72 + gh + quad * 8;
            bh[p] = *(const short8*)(slabh + addr);
            bl[p] = *(const short8*)(slabl + addr);
        }
#pragma unroll
        for (int p = 0; p < 2; ++p) {
            acc[0][p] = __builtin_amdgcn_mfma_f32_16x16x32_bf16(cah0, bh[p], acc[0][p], 0, 0, 0);
            acc[0][p] = __builtin_amdgcn_mfma_f32_16x16x32_bf16(cah0, bl[p], acc[0][p], 0, 0, 0);
            acc[0][p] = __builtin_amdgcn_mfma_f32_16x16x32_bf16(cal0, bh[p], acc[0][p], 0, 0, 0);
            acc[1][p] = __builtin_amdgcn_mfma_f32_16x16x32_bf16(cah1, bh[p], acc[1][p], 0, 0, 0);
            acc[1][p] = __builtin_amdgcn_mfma_f32_16x16x32_bf16(cah1, bl[p], acc[1][p], 0, 0, 0);
            acc[1][p] = __builtin_amdgcn_mfma_f32_16x16x32_bf16(cal1, bh[p], acc[1][p], 0, 0, 0);
        }
        cah0 = nah0; cal0 = nal0; cah1 = nah1; cal1 = nal1;
    }

#pragma unroll
    for (int m = 0; m < 2; ++m) {
#pragma unroll
        for (int reg = 0; reg < 4; ++reg) {
            float v0 = acc[m][0][reg], v1 = acc[m][1][reg];
            float mn = fminf(v0, v1);
            float mx = fmaxf(v0, v1);
            float sm = v0 + v1;
#pragma unroll
            for (int msk = 1; msk <= 8; msk <<= 1) {
                mn = fminf(mn, __shfl_xor(mn, msk, 64));
                mx = fmaxf(mx, __shfl_xor(mx, msk, 64));
                sm += __shfl_xor(sm, msk, 64);
            }
            if (n15 == 0) {
                int o = (wv * 2 + m) * 16 + quad * 4 + reg;
                float* pd = part + ((b * NFC + o) * 32 + y) * 3;
                pd[0] = mn; pd[1] = mx; pd[2] = sm;
            }
        }
    }
}

// --- kfin: 32 row-partials -> score -> argmax -> ig[b*64+f] -----------------
__global__ __launch_bounds__(256) void kfin(const float* __restrict__ part,
                                            const float* __restrict__ S,
                                            int* __restrict__ ig) {
    __shared__ float scl[NFC];
    int b = blockIdx.x, t = threadIdx.x;
    const float* pp = part + (b * NFC + t) * 96;
    float mn = 1e30f, mx = -1e30f, sm = 0.f;
#pragma unroll
    for (int r = 0; r < 32; ++r) {
        mn = fminf(mn, pp[r * 3]);
        mx = fmaxf(mx, pp[r * 3 + 1]);
        sm += pp[r * 3 + 2];
    }
    float s = S[t] * (1.f / 64.f);
    float mnv = (s >= 0.f ? mn : mx) * s;
    float mxv = (s >= 0.f ? mx : mn) * s;
    float smv = sm * s;
    float d = mxv - mnv;
    scl[t] = d > 0.f ? (smv - 1024.f * mnv) / d : 0.f;
    __syncthreads();
    if (t < NFM) {
        float best = scl[t];
        int bi = 0;
#pragma unroll
        for (int n = 1; n < NMX; ++n) {
            float v = scl[n * NFM + t];
            if (v > best) { best = v; bi = n; }   // first-max ties
        }
        ig[b * NFM + t] = bi * NFM + t;
    }
}

// --- kpackO: per-batch gathered weights via LDS chunk staging ---------------
__global__ __launch_bounds__(256) void kpackO(const float* __restrict__ K,
                                              const int* __restrict__ ig,
                                              char* __restrict__ Wob) {
    __shared__ int igL[NFM];
    __shared__ __align__(16) char cbuf[25 * 2048];   // 51200 B
    int ft = blockIdx.x, b = blockIdx.y;
    int t = threadIdx.x;
    if (t < NFM) igL[t] = ig[b * NFM + t];
    __syncthreads();
    int g32 = t & 31, fh = t >> 5;
    int quad = g32 >> 3, j = g32 & 7;
    char* wdst = Wob + b * 409600 + ft * 102400;

    for (int half = 0; half < 2; ++half) {
        int i = igL[half * 32 + g32];
#pragma unroll
        for (int e = 0; e < 2; ++e) {
            int f15 = fh * 2 + e;
            int o = igL[ft * 16 + f15];
            const float* src = K + (i * NFC + o) * KK;
            float v[KK];
            float mn = 1e30f, mx = -1e30f;
#pragma unroll
            for (int k = 0; k < KK; ++k) {
                v[k] = src[k];
                mn = fminf(mn, v[k]);
                mx = fmaxf(mx, v[k]);
            }
            float d = mx - mn;
            float r = d > 0.f ? 1.f / d : 0.f;
            char* base = cbuf + (quad * 16 + f15) * 16 + j * 2;
#pragma unroll
            for (int k = 0; k < KK; ++k) {
                float nv = (v[k] - mn) * r;
                u16 h = f2bfbits(nv);
                u16 l = f2bfbits(nv - bf2f(h));
                *(u16*)(base + k * 2048) = h;
                *(u16*)(base + k * 2048 + 1024) = l;
            }
        }
        __syncthreads();
        for (int idx = t; idx < 3200; idx += 256) {   // 25 chunks x 128 f4
            int ch = idx >> 7, w = idx & 127;
            *(float4*)(wdst + (ch * 2 + half) * 2048 + w * 16) =
                *(const float4*)(cbuf + ch * 2048 + w * 16);
        }
        __syncthreads();
    }
}

// --- kout: MFMA gathered conv. grid (2 xh, 16 yb2, 16 b), 4 blocks/CU -------
__global__ __launch_bounds__(256, 4) void kout(const float* __restrict__ A,
                                               const char* __restrict__ Wob,
                                               float* __restrict__ out) {
    __shared__ u16 slabh[6 * 20 * 72];   // 17280 B
    __shared__ u16 slabl[6 * 20 * 72];
    int t = threadIdx.x;
    int xh = blockIdx.x, yb2 = blockIdx.y, b = blockIdx.z;
    int y0 = yb2 * 2, x0 = xh * 16;
    int lane = t & 63;
    int wv = __builtin_amdgcn_readfirstlane(t >> 6);
    int n15 = lane & 15, quad = lane >> 4;

    const float* Ab = A + b * NFM * HW;
    for (int ry = 0; ry < 6; ++ry) {
        int gy = y0 - 2 + ry;
        bool rowok = (gy >= 0) && (gy < 32);
        for (int c = 0; c < 5; ++c) {
            int id2 = c * 256 + t;               // g*20 + xi
            int g = (id2 * 6554) >> 17;          // exact /20 for id2<1280
            int xi = id2 - g * 20;
            int x = x0 + xi - 2;
            float v = 0.f;
            if (rowok && x >= 0 && x < 32)
                v = Ab[g * HW + gy * 32 + x];
            u16 h = f2bfbits(v);
            u16 l = f2bfbits(v - bf2f(h));
            int idx = (ry * 20 + xi) * 72 + g;
            slabh[idx] = h;
            slabl[idx] = l;
        }
    }
    __syncthreads();

    f32x4 acc[2];
#pragma unroll
    for (int r = 0; r < 2; ++r)
#pragma unroll
        for (int jr = 0; jr < 4; ++jr) acc[r][jr] = 0.f;

    const char* wbase = Wob + b * 409600 + (wv * 50) * 2048 + lane * 16;
    short8 cah = *(const short8*)(wbase);
    short8 cal = *(const short8*)(wbase + 1024);

    for (int ks = 0; ks < 50; ++ks) {
        int ksn = ks < 49 ? ks + 1 : 49;
        const char* nb = wbase + (ksn << 11);
        short8 nah = *(const short8*)nb;
        short8 nal = *(const short8*)(nb + 1024);

        int dydx = ks >> 1;
        int gh = (ks & 1) * 32;
        int dy = dydx / 5, dx = dydx - dy * 5;
#pragma unroll
        for (int r = 0; r < 2; ++r) {
            int addr = ((r + dy) * 20 + n15 + dx) * 72 + gh + quad * 8;
            short8 bh = *(const short8*)(slabh + addr);
            short8 bl = *(const short8*)(slabl + addr);
            acc[r] = __builtin_amdgcn_mfma_f32_16x16x32_bf16(cah, bh, acc[r], 0, 0, 0);
            acc[r] = __builtin_amdgcn_mfma_f32_16x16x32_bf16(cah, bl, acc[r], 0, 0, 0);
            acc[r] = __builtin_amdgcn_mfma_f32_16x16x32_bf16(cal, bh, acc[r], 0, 0, 0);
        }
        cah = nah;
        cal = nal;
    }

#pragma unroll
    for (int r = 0; r < 2; ++r)
#pragma unroll
        for (int reg = 0; reg < 4; ++reg) {
            int f = wv * 16 + quad * 4 + reg;
            out[(b * NFM + f) * HW + (y0 + r) * 32 + x0 + n15] = acc[r][reg] * (1.f / 64.f);
        }
}

extern "C" void kernel_launch(void* const* d_in, const int* in_sizes, int n_in,
                              void* d_out, int out_size, void* d_ws, size_t ws_size,
                              hipStream_t stream) {
    const float* A = (const float*)d_in[0];   // (16,64,32,32) f32
    const float* K = (const float*)d_in[1];   // (256,256,5,5) f32
    const float* S = (const float*)d_in[2];   // (256,) f32
    float* out = (float*)d_out;               // (16,64,32,32) f32

    char* ws = (char*)d_ws;
    char*   Wob   = ws;                         // [0, 6,553,600) written by kpackO
    char*   Wpk   = ws;                         // [0, 1,638,400) dead before kpackO
    float*  wsum2 = (float*)(ws + 1638400);     // [1.64M, 3.28M) dead after kpackW
    float*  part  = (float*)(ws + 6553600);     // [6.55M, 8.13M) 16*256*32*3 f32
    int*    igv   = (int*)(ws + 8126464);       // 4 KB (high-water 8,130,560)

    kprep<<<dim3(256), dim3(256), 0, stream>>>(K, wsum2);
    kpackW<<<dim3(25, 16), dim3(256), 0, stream>>>(wsum2, Wpk);
    kscore<<<dim3(32, 16), dim3(512), 0, stream>>>(A, Wpk, part);
    kfin<<<dim3(16), dim3(256), 0, stream>>>(part, S, igv);
    kpackO<<<dim3(4, 16), dim3(256), 0, stream>>>(K, igv, Wob);
    kout<<<dim3(2, 16, 16), dim3(256), 0, stream>>>(A, Wob, out);
}

// Round 13
// 150.418 us; speedup vs baseline: 1.0717x; 1.0717x over previous
//
#include <hip/hip_runtime.h>

// LaterallyConnectedLayer: B=16, NUM_FM=64, N=4, NF=256, H=W=32, KS=5. fp32 I/O.
//   w1[i][o][k]   = minmax5x5( K[i][o] )
//   wsum[o][g][k] = sum_n w1[64n+g][o][k]
//   score[b,o]    = (sum-1024*min)/(max-min) over conv_same(A[b,:],wsum[o,:])*S[o]
//   n*[b,f]       = argmax_n score[b,64n+f]
//   out[b,f]      = (1/64) sum_g conv_same(A[b,g], w1[ig_g][ig_f]), ig_x = 64n*_x + x
// Both convs are implicit GEMMs on mfma_f32_16x16x32_bf16 with fp32 hi/lo split
// (hh+hl+lh). K-dim order: k_global = dydx*64 + g -> chunk ks = dydx*2+(g>=32),
// in-chunk k = quad*8+j with g = (ks&1)*32+quad*8+j. Fragment layouts per m89.
// kscore blocks cover FULL M (256 o) x 2 rows: each weight chunk read once per
// CU (L2 weight stream 1.6 MB/CU, under the 19.4 us MFMA floor); wave = 2 M-
// tiles x 4 npos -> 171 weight-B/MFMA.

#define NFM 64
#define NMX 4
#define NFC 256
#define HW 1024
#define KK 25

typedef unsigned short u16;
typedef short short8 __attribute__((ext_vector_type(8)));
typedef float f32x4 __attribute__((ext_vector_type(4)));

__device__ __forceinline__ u16 f2bfbits(float f) {
    unsigned int u = __float_as_uint(f);
    u += 0x7fffu + ((u >> 16) & 1u);   // RNE
    return (u16)(u >> 16);
}
__device__ __forceinline__ float bf2f(u16 v) {
    return __uint_as_float(((unsigned int)v) << 16);
}

// --- kprep: wsum2[g][k][o] = sum_n minmax5x5(K[64n+g][o]) -------------------
__global__ __launch_bounds__(256) void kprep(const float* __restrict__ K,
                                             float* __restrict__ wsum2) {
    __shared__ __align__(16) float buf[64 * KK];
    int g = blockIdx.x & 63, o0 = (blockIdx.x >> 6) * 64;
    int t = threadIdx.x;
    float wacc[KK];
#pragma unroll
    for (int k = 0; k < KK; ++k) wacc[k] = 0.f;

    for (int n = 0; n < NMX; ++n) {
        int i = n * NFM + g;
        const float4* src = (const float4*)(K + (i * NFC + o0) * KK);  // 400 f4
        __syncthreads();
        ((float4*)buf)[t] = src[t];
        if (t < 144) ((float4*)buf)[t + 256] = src[t + 256];
        __syncthreads();
        if (t < 64) {
            float v[KK];
            float mn = 1e30f, mx = -1e30f;
#pragma unroll
            for (int k = 0; k < KK; ++k) {
                v[k] = buf[t * KK + k];
                mn = fminf(mn, v[k]);
                mx = fmaxf(mx, v[k]);
            }
            float d = mx - mn;
            float r = d > 0.f ? 1.f / d : 0.f;
#pragma unroll
            for (int k = 0; k < KK; ++k) wacc[k] += (v[k] - mn) * r;
        }
    }
    __syncthreads();
    if (t < 64) {
#pragma unroll
        for (int k = 0; k < KK; ++k) buf[t * KK + k] = wacc[k];
    }
    __syncthreads();
    for (int idx = t; idx < 1600; idx += 256) {
        int k = idx >> 6, ol = idx & 63;
        wsum2[(g * KK + k) * NFC + o0 + ol] = buf[ol * KK + k];
    }
}

// --- kpackW: wsum2 -> Wpk via LDS transpose. grid (25 dydx, 16 ot) ----------
__global__ __launch_bounds__(256) void kpackW(const float* __restrict__ wsum2,
                                              char* __restrict__ Wpk) {
    __shared__ float wlds[64 * 16];
    int dydx = blockIdx.x, ot = blockIdx.y, t = threadIdx.x;
    int o15 = t & 15, gq = t >> 4;
#pragma unroll
    for (int e = 0; e < 4; ++e) {
        int g = e * 16 + gq;
        wlds[g * 16 + o15] = wsum2[(g * KK + dydx) * NFC + ot * 16 + o15];
    }
    __syncthreads();
    int gh = t >> 7, l = t & 63;      // gh 0..1, lane l
    int quad = l >> 4, oo = l & 15;
    short8 hs, ls;
#pragma unroll
    for (int j = 0; j < 8; ++j) {
        float v = wlds[(gh * 32 + quad * 8 + j) * 16 + oo];
        u16 h = f2bfbits(v);
        hs[j] = (short)h;
        ls[j] = (short)f2bfbits(v - bf2f(h));
    }
    char* cb = Wpk + (ot * 50 + dydx * 2 + gh) * 2048 + l * 16;
    *(short8*)cb = hs;
    *(short8*)(cb + 1024) = ls;
}

// --- kscore: grid (16 y2, 16 b), 512 thr, 1 block/CU ------------------------
// Block = full M (16 tiles) x 2 rows x 32 px. Wave = 2 M-tiles x 4 npos
// (2 rows x 2 ntiles); B-frags shared across both M-tiles in-register;
// next-ks weight prefetch. Weight chunks read once per block.
__global__ __launch_bounds__(512, 2) void kscore(const float* __restrict__ A,
                                                 const char* __restrict__ Wpk,
                                                 float4* __restrict__ part) {
    __shared__ u16 slabh[6 * 36 * 72];   // 31104 B
    __shared__ u16 slabl[6 * 36 * 72];
    int t = threadIdx.x;
    int y2 = blockIdx.x, b = blockIdx.y;
    int y0 = y2 * 2;
    int lane = t & 63;
    int wv = __builtin_amdgcn_readfirstlane(t >> 6);   // 0..7 = M-tile pair
    int n15 = lane & 15, quad = lane >> 4;

    const float* Ab = A + b * NFM * HW;
    for (int ry = 0; ry < 6; ++ry) {
        int gy = y0 - 2 + ry;
        bool rowok = (gy >= 0) && (gy < 32);
        for (int c = 0; c < 5; ++c) {
            int id2 = c * 512 + t;               // g*36 + xi, < 2304
            if (id2 < 2304) {
                int g = (id2 * 3641) >> 17;      // exact /36 for id2<2304
                int xi = id2 - g * 36;
                float v = 0.f;
                if (rowok && xi >= 2 && xi < 34)
                    v = Ab[g * HW + gy * 32 + xi - 2];
                u16 h = f2bfbits(v);
                u16 l = f2bfbits(v - bf2f(h));
                int idx = (ry * 36 + xi) * 72 + g;
                slabh[idx] = h;
                slabl[idx] = l;
            }
        }
    }
    __syncthreads();

    f32x4 acc[2][4];
#pragma unroll
    for (int m = 0; m < 2; ++m)
#pragma unroll
        for (int p = 0; p < 4; ++p)
#pragma unroll
            for (int r = 0; r < 4; ++r) acc[m][p][r] = 0.f;

    const char* wbase0 = Wpk + (wv * 2) * 50 * 2048 + lane * 16;
    const char* wbase1 = wbase0 + 50 * 2048;
    short8 cah0 = *(const short8*)(wbase0);
    short8 cal0 = *(const short8*)(wbase0 + 1024);
    short8 cah1 = *(const short8*)(wbase1);
    short8 cal1 = *(const short8*)(wbase1 + 1024);

    for (int ks = 0; ks < 50; ++ks) {
        int ksn = ks < 49 ? ks + 1 : 49;
        const char* nb0 = wbase0 + (ksn << 11);
        const char* nb1 = wbase1 + (ksn << 11);
        short8 nah0 = *(const short8*)nb0;
        short8 nal0 = *(const short8*)(nb0 + 1024);
        short8 nah1 = *(const short8*)nb1;
        short8 nal1 = *(const short8*)(nb1 + 1024);

        int dydx = ks >> 1;
        int gh = (ks & 1) * 32;
        int dy = dydx / 5, dx = dydx - dy * 5;
        short8 bh[4], bl[4];
#pragma unroll
        for (int p = 0; p < 4; ++p) {
            int r = p >> 1, nt = p & 1;
            int addr = ((r + dy) * 36 + nt * 16 + n15 + dx) * 72 + gh + quad * 8;
            bh[p] = *(const short8*)(slabh + addr);
            bl[p] = *(const short8*)(slabl + addr);
        }
#pragma unroll
        for (int p = 0; p < 4; ++p) {
            acc[0][p] = __builtin_amdgcn_mfma_f32_16x16x32_bf16(cah0, bh[p], acc[0][p], 0, 0, 0);
            acc[0][p] = __builtin_amdgcn_mfma_f32_16x16x32_bf16(cah0, bl[p], acc[0][p], 0, 0, 0);
            acc[0][p] = __builtin_amdgcn_mfma_f32_16x16x32_bf16(cal0, bh[p], acc[0][p], 0, 0, 0);
            acc[1][p] = __builtin_amdgcn_mfma_f32_16x16x32_bf16(cah1, bh[p], acc[1][p], 0, 0, 0);
            acc[1][p] = __builtin_amdgcn_mfma_f32_16x16x32_bf16(cah1, bl[p], acc[1][p], 0, 0, 0);
            acc[1][p] = __builtin_amdgcn_mfma_f32_16x16x32_bf16(cal1, bh[p], acc[1][p], 0, 0, 0);
        }
        cah0 = nah0; cal0 = nal0; cah1 = nah1; cal1 = nal1;
    }

#pragma unroll
    for (int m = 0; m < 2; ++m) {
#pragma unroll
        for (int reg = 0; reg < 4; ++reg) {
            float v0 = acc[m][0][reg], v1 = acc[m][1][reg];
            float v2 = acc[m][2][reg], v3 = acc[m][3][reg];
            float mn = fminf(fminf(v0, v1), fminf(v2, v3));
            float mx = fmaxf(fmaxf(v0, v1), fmaxf(v2, v3));
            float sm = (v0 + v1) + (v2 + v3);
#pragma unroll
            for (int msk = 1; msk <= 8; msk <<= 1) {
                mn = fminf(mn, __shfl_xor(mn, msk, 64));
                mx = fmaxf(mx, __shfl_xor(mx, msk, 64));
                sm += __shfl_xor(sm, msk, 64);
            }
            if (n15 == 0) {
                int o = (wv * 2 + m) * 16 + quad * 4 + reg;
                part[(b * NFC + o) * 16 + y2] = make_float4(mn, mx, sm, 0.f);
            }
        }
    }
}

// --- kpackO: fused score-finalize + argmax + per-batch weight pack ----------
// grid (4 ft, 16 b), 256 thr. Prologue: each thread reduces 16 row-partials
// for one o -> score; t<64 computes argmax -> igL (LDS only). Then pack.
__global__ __launch_bounds__(256) void kpackO(const float* __restrict__ K,
                                              const float4* __restrict__ part,
                                              const float* __restrict__ S,
                                              char* __restrict__ Wob) {
    __shared__ float scl[NFC];
    __shared__ int igL[NFM];
    __shared__ __align__(16) char cbuf[25 * 2048];   // 51200 B
    int ft = blockIdx.x, b = blockIdx.y;
    int t = threadIdx.x;
    {
        const float4* pp = part + (b * NFC + t) * 16;
        float mn = 1e30f, mx = -1e30f, sm = 0.f;
#pragma unroll
        for (int r = 0; r < 16; ++r) {
            float4 p = pp[r];
            mn = fminf(mn, p.x);
            mx = fmaxf(mx, p.y);
            sm += p.z;
        }
        float s = S[t] * (1.f / 64.f);
        float mnv = (s >= 0.f ? mn : mx) * s;
        float mxv = (s >= 0.f ? mx : mn) * s;
        float smv = sm * s;
        float d = mxv - mnv;
        scl[t] = d > 0.f ? (smv - 1024.f * mnv) / d : 0.f;
    }
    __syncthreads();
    if (t < NFM) {
        float best = scl[t];
        int bi = 0;
#pragma unroll
        for (int n = 1; n < NMX; ++n) {
            float v = scl[n * NFM + t];
            if (v > best) { best = v; bi = n; }   // first-max ties
        }
        igL[t] = bi * NFM + t;
    }
    __syncthreads();

    int g32 = t & 31, fh = t >> 5;
    int quad = g32 >> 3, j = g32 & 7;
    char* wdst = Wob + b * 409600 + ft * 102400;

    for (int half = 0; half < 2; ++half) {
        int i = igL[half * 32 + g32];
#pragma unroll
        for (int e = 0; e < 2; ++e) {
            int f15 = fh * 2 + e;
            int o = igL[ft * 16 + f15];
            const float* src = K + (i * NFC + o) * KK;
            float v[KK];
            float mn = 1e30f, mx = -1e30f;
#pragma unroll
            for (int k = 0; k < KK; ++k) {
                v[k] = src[k];
                mn = fminf(mn, v[k]);
                mx = fmaxf(mx, v[k]);
            }
            float d = mx - mn;
            float r = d > 0.f ? 1.f / d : 0.f;
            char* base = cbuf + (quad * 16 + f15) * 16 + j * 2;
#pragma unroll
            for (int k = 0; k < KK; ++k) {
                float nv = (v[k] - mn) * r;
                u16 h = f2bfbits(nv);
                u16 l = f2bfbits(nv - bf2f(h));
                *(u16*)(base + k * 2048) = h;
                *(u16*)(base + k * 2048 + 1024) = l;
            }
        }
        __syncthreads();
        for (int idx = t; idx < 3200; idx += 256) {   // 25 chunks x 128 f4
            int ch = idx >> 7, w = idx & 127;
            *(float4*)(wdst + (ch * 2 + half) * 2048 + w * 16) =
                *(const float4*)(cbuf + ch * 2048 + w * 16);
        }
        __syncthreads();
    }
}

// --- kout: MFMA gathered conv. grid (2 xh, 16 yb2, 16 b) --------------------
__global__ __launch_bounds__(256, 4) void kout(const float* __restrict__ A,
                                               const char* __restrict__ Wob,
                                               float* __restrict__ out) {
    __shared__ u16 slabh[6 * 20 * 72];   // 17280 B
    __shared__ u16 slabl[6 * 20 * 72];
    int t = threadIdx.x;
    int xh = blockIdx.x, yb2 = blockIdx.y, b = blockIdx.z;
    int y0 = yb2 * 2, x0 = xh * 16;
    int lane = t & 63;
    int wv = __builtin_amdgcn_readfirstlane(t >> 6);
    int n15 = lane & 15, quad = lane >> 4;

    const float* Ab = A + b * NFM * HW;
    for (int ry = 0; ry < 6; ++ry) {
        int gy = y0 - 2 + ry;
        bool rowok = (gy >= 0) && (gy < 32);
        for (int c = 0; c < 5; ++c) {
            int id2 = c * 256 + t;               // g*20 + xi
            int g = (id2 * 6554) >> 17;          // exact /20 for id2<1280
            int xi = id2 - g * 20;
            int x = x0 + xi - 2;
            float v = 0.f;
            if (rowok && x >= 0 && x < 32)
                v = Ab[g * HW + gy * 32 + x];
            u16 h = f2bfbits(v);
            u16 l = f2bfbits(v - bf2f(h));
            int idx = (ry * 20 + xi) * 72 + g;
            slabh[idx] = h;
            slabl[idx] = l;
        }
    }
    __syncthreads();

    f32x4 acc[2];
#pragma unroll
    for (int r = 0; r < 2; ++r)
#pragma unroll
        for (int jr = 0; jr < 4; ++jr) acc[r][jr] = 0.f;

    const char* wbase = Wob + b * 409600 + (wv * 50) * 2048 + lane * 16;
    short8 cah = *(const short8*)(wbase);
    short8 cal = *(const short8*)(wbase + 1024);

    for (int ks = 0; ks < 50; ++ks) {
        int ksn = ks < 49 ? ks + 1 : 49;
        const char* nb = wbase + (ksn << 11);
        short8 nah = *(const short8*)nb;
        short8 nal = *(const short8*)(nb + 1024);

        int dydx = ks >> 1;
        int gh = (ks & 1) * 32;
        int dy = dydx / 5, dx = dydx - dy * 5;
#pragma unroll
        for (int r = 0; r < 2; ++r) {
            int addr = ((r + dy) * 20 + n15 + dx) * 72 + gh + quad * 8;
            short8 bh = *(const short8*)(slabh + addr);
            short8 bl = *(const short8*)(slabl + addr);
            acc[r] = __builtin_amdgcn_mfma_f32_16x16x32_bf16(cah, bh, acc[r], 0, 0, 0);
            acc[r] = __builtin_amdgcn_mfma_f32_16x16x32_bf16(cah, bl, acc[r], 0, 0, 0);
            acc[r] = __builtin_amdgcn_mfma_f32_16x16x32_bf16(cal, bh, acc[r], 0, 0, 0);
        }
        cah = nah;
        cal = nal;
    }

#pragma unroll
    for (int r = 0; r < 2; ++r)
#pragma unroll
        for (int reg = 0; reg < 4; ++reg) {
            int f = wv * 16 + quad * 4 + reg;
            out[(b * NFM + f) * HW + (y0 + r) * 32 + x0 + n15] = acc[r][reg] * (1.f / 64.f);
        }
}

extern "C" void kernel_launch(void* const* d_in, const int* in_sizes, int n_in,
                              void* d_out, int out_size, void* d_ws, size_t ws_size,
                              hipStream_t stream) {
    const float* A = (const float*)d_in[0];   // (16,64,32,32) f32
    const float* K = (const float*)d_in[1];   // (256,256,5,5) f32
    const float* S = (const float*)d_in[2];   // (256,) f32
    float* out = (float*)d_out;               // (16,64,32,32) f32

    char* ws = (char*)d_ws;
    char*   Wob   = ws;                         // [0, 6,553,600) written by kpackO
    char*   Wpk   = ws;                         // [0, 1,638,400) dead before kpackO
    float*  wsum2 = (float*)(ws + 1638400);     // [1.64M, 3.28M) dead after kpackW
    float4* part  = (float4*)(ws + 6553600);    // [6.55M, 7.60M) 16*256*16 f4

    kprep<<<dim3(256), dim3(256), 0, stream>>>(K, wsum2);
    kpackW<<<dim3(25, 16), dim3(256), 0, stream>>>(wsum2, Wpk);
    kscore<<<dim3(16, 16), dim3(512), 0, stream>>>(A, Wpk, part);
    kpackO<<<dim3(4, 16), dim3(256), 0, stream>>>(K, part, S, Wob);
    kout<<<dim3(2, 16, 16), dim3(256), 0, stream>>>(A, Wob, out);
}